// Round 17
// baseline (628.710 us; speedup 1.0000x reference)
//
#include <hip/hip_runtime.h>
#include <hip/hip_bf16.h>

typedef __attribute__((ext_vector_type(8))) short short8;
typedef __attribute__((ext_vector_type(4))) float floatx4;
typedef __attribute__((ext_vector_type(16))) float floatx16;

__device__ __forceinline__ unsigned short f2bf(float x) {
  __hip_bfloat16 h = __float2bfloat16(x);
  return __builtin_bit_cast(unsigned short, h);
}
__device__ __forceinline__ float bf2f(unsigned short u) {
  return __builtin_bit_cast(float, (unsigned int)u << 16);
}

// ---------------------------------------------------------------------
// X (fp32) -> bf16 copy
// ---------------------------------------------------------------------
__global__ __launch_bounds__(256) void cvt_x_kernel(
    const float* __restrict__ X, unsigned short* __restrict__ Xbf, int n) {
  int i = blockIdx.x * 256 + threadIdx.x;
  if (i < n) Xbf[i] = f2bf(X[i]);
}

// ---------------------------------------------------------------------
// Pack extended weights [W | root] into MFMA B-fragment order.
// K2=0 packs just a 64x64 matrix from `root`.
// ---------------------------------------------------------------------
__global__ __launch_bounds__(256) void pack_b_kernel(
    const float* __restrict__ W, const float* __restrict__ root,
    unsigned short* __restrict__ Bpk, int K2) {
  int R = (K2 + 1) * 64;
  int total = 64 * R;
  int i = blockIdx.x * 256 + threadIdx.x;
  if (i >= total) return;
  int j = i & 7;
  int lane = (i >> 3) & 63;
  int rest = i >> 9;            // kc*4 + wv
  int wv = rest & 3, kc = rest >> 2;
  int o = wv * 16 + (lane & 15);
  int r = kc * 32 + ((lane >> 4) & 3) * 8 + j;
  int k = r >> 6, d = r & 63;
  float v = (k < K2) ? W[(k << 12) + (d << 6) + o] : root[(d << 6) + o];
  Bpk[i] = f2bf(v);
}

// ---------------------------------------------------------------------
// CSR build (padded to 16-edge chunks per node)
// ---------------------------------------------------------------------
__global__ __launch_bounds__(256) void zero_int_kernel(int* __restrict__ p, int n) {
  int i = blockIdx.x * 256 + threadIdx.x;
  if (i < n) p[i] = 0;
}

__global__ __launch_bounds__(256) void hist_kernel(
    const int* __restrict__ dst, int* __restrict__ deg, int nE) {
  int e = blockIdx.x * 256 + threadIdx.x;
  if (e < nE) atomicAdd(&deg[dst[e]], 1);
}

__global__ __launch_bounds__(256) void blocksum_kernel(
    const int* __restrict__ deg, int* __restrict__ partial, int N) {
  __shared__ int s[256];
  int t = threadIdx.x, i = blockIdx.x * 256 + t;
  s[t] = (i < N) ? ((deg[i] + 15) & ~15) : 0;   // padded degree
  __syncthreads();
  for (int off = 128; off > 0; off >>= 1) {
    if (t < off) s[t] += s[t + off];
    __syncthreads();
  }
  if (t == 0) partial[blockIdx.x] = s[0];
}

__global__ __launch_bounds__(256) void scanpartials_kernel(
    int* __restrict__ partial, int nb) {
  __shared__ int s[256];
  int t = threadIdx.x;
  int v = (t < nb) ? partial[t] : 0;
  s[t] = v;
  __syncthreads();
  for (int off = 1; off < 256; off <<= 1) {
    int x = (t >= off) ? s[t - off] : 0;
    __syncthreads();
    s[t] += x;
    __syncthreads();
  }
  if (t < nb) partial[t] = s[t] - v;
}

__global__ __launch_bounds__(256) void blockscan_kernel(
    const int* __restrict__ deg, const int* __restrict__ partial,
    int* __restrict__ prow, int* __restrict__ cursor, int N) {
  __shared__ int s[256];
  int t = threadIdx.x, i = blockIdx.x * 256 + t;
  int v = (i < N) ? ((deg[i] + 15) & ~15) : 0;
  s[t] = v;
  __syncthreads();
  for (int off = 1; off < 256; off <<= 1) {
    int x = (t >= off) ? s[t - off] : 0;
    __syncthreads();
    s[t] += x;
    __syncthreads();
  }
  if (i < N) {
    int excl = s[t] - v + partial[blockIdx.x];
    prow[i] = excl;
    cursor[i] = excl;
    if (i == N - 1) prow[N] = excl + v;
  }
}

// ---------------------------------------------------------------------
// Scatter: per edge, write src-offset + precomputed bucket coefficients
// in MFMA-fragment (chunk-transposed) order.
//   cT3[chunk][col<16][kp] (cols>=9 are zero),  cT5[chunk][col<32][kp]
// Coefficient values identical to what phase 1 used to compute on the fly.
// ---------------------------------------------------------------------
__global__ __launch_bounds__(256) void scatter_coeff_kernel(
    const int* __restrict__ dst, const int* __restrict__ src,
    const float* __restrict__ attr, int* __restrict__ cursor,
    int* __restrict__ offs, unsigned short* __restrict__ cT3,
    unsigned short* __restrict__ cT5, int nE) {
  int e = blockIdx.x * 256 + threadIdx.x;
  if (e >= nE) return;
  int pos = atomicAdd(&cursor[dst[e]], 1);
  int chunk = pos >> 4, kp = pos & 15;
  float2 a = *(const float2*)&attr[2 * e];
  offs[pos] = src[e] * 64;
  {  // K=3
    float u = a.x * 2.f, v = a.y * 2.f;
    int l0 = min((int)u, 1), l1 = min((int)v, 1);
    float f0 = u - (float)l0, f1 = v - (float)l1;
    for (int col = 0; col < 16; ++col) {
      int mi0 = (col < 9) ? (col % 3) : -3;
      int mi1 = (col < 9) ? (col / 3) : -3;
      float su = (mi0 == l0) ? (1.f - f0) : ((mi0 == l0 + 1) ? f0 : 0.f);
      float sv = (mi1 == l1) ? (1.f - f1) : ((mi1 == l1 + 1) ? f1 : 0.f);
      cT3[(size_t)chunk * 256 + col * 16 + kp] = f2bf(su * sv);
    }
  }
  {  // K=5
    float u = a.x * 4.f, v = a.y * 4.f;
    int l0 = min((int)u, 3), l1 = min((int)v, 3);
    float f0 = u - (float)l0, f1 = v - (float)l1;
    for (int col = 0; col < 32; ++col) {
      int mi0 = (col < 25) ? (col % 5) : -3;
      int mi1 = (col < 25) ? (col / 5) : -3;
      float su = (mi0 == l0) ? (1.f - f0) : ((mi0 == l0 + 1) ? f0 : 0.f);
      float sv = (mi1 == l1) ? (1.f - f1) : ((mi1 == l1 + 1) ? f1 : 0.f);
      cT5[(size_t)chunk * 512 + col * 16 + kp] = f2bf(su * sv);
    }
  }
}

// Zero the padding slots (coeff 0 => exact no-op contributions; off=0 safe).
__global__ __launch_bounds__(256) void pad_kernel(
    const int* __restrict__ deg, const int* __restrict__ prow,
    int* __restrict__ offs, unsigned short* __restrict__ cT3,
    unsigned short* __restrict__ cT5, int N) {
  int i = blockIdx.x * 256 + threadIdx.x;
  int node = i >> 4, s = i & 15;
  if (node >= N) return;
  int d = deg[node];
  int pd = (d + 15) & ~15;
  if (d + s >= pd) return;
  int pos = prow[node] + d + s;
  int chunk = pos >> 4, kp = pos & 15;
  offs[pos] = 0;
  for (int col = 0; col < 16; ++col)
    cT3[(size_t)chunk * 256 + col * 16 + kp] = 0;
  for (int col = 0; col < 32; ++col)
    cT5[(size_t)chunk * 512 + col * 16 + kp] = 0;
}

// ---------------------------------------------------------------------
// FUSED spline layer: block = 4 waves = 16 dst nodes (4 nodes/wave).
// Phase 1: per 16-edge chunk, A-fragment is ONE coalesced 16B/lane load
//   from the precomputed cT stream (no per-edge VALU coefficient math),
//   offs are 8 broadcast loads, then 16 bf16 row-gathers -> 2 MFMAs.
// Phase 2: out[16x64] = ELU([Az | X] @ Bpk + b); root row read from input.
// ---------------------------------------------------------------------
template <int K, int K2, int OUTBF>
__global__ __launch_bounds__(256) void spline_layer_kernel(
    const unsigned short* __restrict__ cT, const int* __restrict__ offs,
    const int* __restrict__ prow, const int* __restrict__ deg,
    const unsigned short* __restrict__ Xbf, const unsigned short* __restrict__ Bpk,
    const float* __restrict__ bias, void* __restrict__ outv, int N) {
  constexpr int RZ = K2 * 64;          // bucket columns: 576 / 1600
  constexpr int AS = RZ + 8;           // LDS row stride (shorts)
  constexpr int NKZ = RZ / 32;         // 18 / 50
  constexpr int NKC = (K2 + 1) * 2;    // 20 / 52
  constexpr int CSTRIDE = (K == 3) ? 256 : 512;
  __shared__ unsigned short As[16 * AS];
  const int t = threadIdx.x, w = t >> 6, lane = t & 63;
  const int nodeBase = blockIdx.x * 16;

  const int col = lane & 31, half = lane >> 5;

  // ---------- phase 1: zbuild 4 nodes per wave into LDS ----------
  for (int g = 0; g < 4; ++g) {
    const int row = w * 4 + g;
    const int node = nodeBase + row;
    if (node < N) {
      floatx16 d0, d1;
#pragma unroll
      for (int i = 0; i < 16; ++i) { d0[i] = 0.f; d1[i] = 0.f; }

      const int beg = prow[node], endp = prow[node + 1];
      for (int c0 = beg; c0 < endp; c0 += 16) {
        const int chunk = c0 >> 4;
        short8 A;
        if (K == 3) {
          short8 tmp = *(const short8*)&cT[(size_t)chunk * CSTRIDE +
                                           (col & 15) * 16 + half * 8];
          short8 zero = {0, 0, 0, 0, 0, 0, 0, 0};
          A = (col < 16) ? tmp : zero;
        } else {
          A = *(const short8*)&cT[(size_t)chunk * CSTRIDE + col * 16 + half * 8];
        }
        int offj[8];
#pragma unroll
        for (int j = 0; j < 8; ++j) offj[j] = offs[c0 + half * 8 + j];
        short8 Blo, Bhi;
#pragma unroll
        for (int j = 0; j < 8; ++j) {
          Blo[j] = (short)Xbf[offj[j] + col];
          Bhi[j] = (short)Xbf[offj[j] + 32 + col];
        }
        d0 = __builtin_amdgcn_mfma_f32_32x32x16_bf16(A, Blo, d0, 0, 0, 0);
        d1 = __builtin_amdgcn_mfma_f32_32x32x16_bf16(A, Bhi, d1, 0, 0, 0);
      }

      const float inv = 1.f / (float)max(deg[node], 1);
#pragma unroll
      for (int reg = 0; reg < 16; ++reg) {
        int r = (reg & 3) + 8 * (reg >> 2) + 4 * half;
        if (r < K2) {
          As[row * AS + r * 64 + col] = f2bf(d0[reg] * inv);
          As[row * AS + r * 64 + 32 + col] = f2bf(d1[reg] * inv);
        }
      }
    } else {
      for (int i = lane; i < RZ; i += 64) As[row * AS + i] = 0;
    }
  }
  __syncthreads();

  // ---------- phase 2: 16 x R x 64 GEMM + bias + ELU ----------
  const int mrow = lane & 15, q = lane >> 4;
  const int anode = min(nodeBase + mrow, N - 1);  // root row (clamped; garbage
                                                  // only hits discarded rows)
  floatx4 acc = {0.f, 0.f, 0.f, 0.f};
#pragma unroll
  for (int kc = 0; kc < NKC; ++kc) {
    short8 a;
    if (kc < NKZ)
      a = *(const short8*)&As[mrow * AS + kc * 32 + q * 8];
    else
      a = *(const short8*)&Xbf[(size_t)anode * 64 + (kc - NKZ) * 32 + q * 8];
    short8 b = *(const short8*)&Bpk[(((size_t)kc * 4 + w) * 64 + lane) * 8];
    acc = __builtin_amdgcn_mfma_f32_16x16x32_bf16(a, b, acc, 0, 0, 0);
  }

  const int o = w * 16 + mrow;
  const float bv = bias[o];
#pragma unroll
  for (int reg = 0; reg < 4; ++reg) {
    int node = nodeBase + q * 4 + reg;
    if (node < N) {
      float v = acc[reg] + bv;
      v = v > 0.f ? v : (expf(v) - 1.f);
      if (OUTBF)
        ((unsigned short*)outv)[(size_t)node * 64 + o] = f2bf(v);
      else
        ((float*)outv)[(size_t)node * 64 + o] = v;
    }
  }
}

// ---------------------------------------------------------------------
// FUSED MLP head: out = relu( relu(h2 @ m1w + m1b) @ m2w + m2b )
// ---------------------------------------------------------------------
__global__ __launch_bounds__(256) void head_kernel(
    const unsigned short* __restrict__ h2bf, const unsigned short* __restrict__ m1pk,
    const float* __restrict__ m1b, const float* __restrict__ m2w,
    const float* __restrict__ m2b, float* __restrict__ out, int N) {
  __shared__ unsigned short Hs[64 * 72];
  __shared__ unsigned short Ts[64 * 72];
  __shared__ float W2s[512];
  const int t = threadIdx.x, w = t >> 6, lane = t & 63;
  const int n0 = blockIdx.x * 64;

  for (int i = t; i < 512; i += 256) {
    int row = i >> 3, cg = i & 7;
    int n = n0 + row;
    floatx4 val = {0.f, 0.f, 0.f, 0.f};
    if (n < N) val = *(const floatx4*)&h2bf[(size_t)n * 64 + cg * 8];
    *(floatx4*)&Hs[row * 72 + cg * 8] = val;
  }
  for (int i = t; i < 512; i += 256) W2s[i] = m2w[i];
  __syncthreads();

  const int mrow = lane & 15, q = lane >> 4;
  const int o = w * 16 + mrow;
  const float bv = m1b[o];
#pragma unroll
  for (int rg = 0; rg < 4; ++rg) {
    floatx4 acc = {0.f, 0.f, 0.f, 0.f};
#pragma unroll
    for (int kc = 0; kc < 2; ++kc) {
      short8 a = *(const short8*)&Hs[(rg * 16 + mrow) * 72 + kc * 32 + q * 8];
      short8 b = *(const short8*)&m1pk[(((size_t)kc * 4 + w) * 64 + lane) * 8];
      acc = __builtin_amdgcn_mfma_f32_16x16x32_bf16(a, b, acc, 0, 0, 0);
    }
#pragma unroll
    for (int reg = 0; reg < 4; ++reg) {
      int row = rg * 16 + q * 4 + reg;
      float v = acc[reg] + bv;
      Ts[row * 72 + o] = f2bf(v > 0.f ? v : 0.f);
    }
  }
  __syncthreads();

  for (int i = t; i < 512; i += 256) {
    int nl = i >> 3, c = i & 7;
    int n = n0 + nl;
    if (n >= N) continue;
    float s = m2b[c];
    for (int d = 0; d < 64; ++d) s += bf2f(Ts[nl * 72 + d]) * W2s[d * 8 + c];
    out[(size_t)n * 8 + c] = s > 0.f ? s : 0.f;
  }
}

// ---------------------------------------------------------------------
extern "C" void kernel_launch(void* const* d_in, const int* in_sizes, int n_in,
                              void* d_out, int out_size, void* d_ws, size_t ws_size,
                              hipStream_t stream) {
  const float* x     = (const float*)d_in[0];
  const int*   ei    = (const int*)d_in[1];
  const float* attr  = (const float*)d_in[2];
  const float* W1    = (const float*)d_in[3];
  const float* root1 = (const float*)d_in[4];
  const float* b1    = (const float*)d_in[5];
  const float* W2    = (const float*)d_in[6];
  const float* root2 = (const float*)d_in[7];
  const float* b2    = (const float*)d_in[8];
  const float* m1w   = (const float*)d_in[9];
  const float* m1b   = (const float*)d_in[10];
  const float* m2w   = (const float*)d_in[11];
  const float* m2b   = (const float*)d_in[12];

  const int N  = in_sizes[0] / 64;
  const int nE = in_sizes[1] / 2;
  const int* src  = ei;
  const int* dstv = ei + nE;
  float* out = (float*)d_out;

  // workspace layout
  const size_t maxPE = (size_t)nE + 16 * (size_t)N;   // padded-edge bound
  const size_t maxChunks = maxPE / 16;
  int* deg     = (int*)d_ws;
  int* prow    = deg + N;                 // N+1
  int* cursor  = prow + (N + 1);
  int* partial = cursor + N;              // 256
  char* pbase = (char*)(partial + 256);
  pbase = (char*)(((uintptr_t)pbase + 15) & ~(uintptr_t)15);
  int* offs = (int*)pbase;                              // maxPE
  unsigned short* cT3 = (unsigned short*)(offs + maxPE);  // maxChunks*256
  unsigned short* cT5 = cT3 + maxChunks * 256;            // maxChunks*512
  unsigned short* Xbf  = cT5 + maxChunks * 512;           // N*64
  unsigned short* h1bf = Xbf + (size_t)N * 64;            // N*64
  unsigned short* h2bf = h1bf + (size_t)N * 64;           // N*64
  unsigned short* Bpk1 = h2bf + (size_t)N * 64;           // 64*640
  unsigned short* Bpk2 = Bpk1 + 64 * 640;                 // 64*1664
  unsigned short* m1pk = Bpk2 + 64 * 1664;                // 64*64

  dim3 blk(256);
  int nbN  = (N + 255) / 256;
  int nbE  = (nE + 255) / 256;
  int nbP  = (N * 16 + 255) / 256;
  int nbF  = (N + 15) / 16;
  int nbH  = (N + 63) / 64;

  // ----- CSR build (padded; graph identical both layers) -----
  zero_int_kernel<<<nbN, blk, 0, stream>>>(deg, N);
  hist_kernel<<<nbE, blk, 0, stream>>>(dstv, deg, nE);
  blocksum_kernel<<<nbN, blk, 0, stream>>>(deg, partial, N);
  scanpartials_kernel<<<1, blk, 0, stream>>>(partial, nbN);
  blockscan_kernel<<<nbN, blk, 0, stream>>>(deg, partial, prow, cursor, N);
  scatter_coeff_kernel<<<nbE, blk, 0, stream>>>(dstv, src, attr, cursor,
                                                offs, cT3, cT5, nE);
  pad_kernel<<<nbP, blk, 0, stream>>>(deg, prow, offs, cT3, cT5, N);

  // ----- weight / input prep -----
  pack_b_kernel<<<(64 * 640 + 255) / 256, blk, 0, stream>>>(W1, root1, Bpk1, 9);
  pack_b_kernel<<<(64 * 1664 + 255) / 256, blk, 0, stream>>>(W2, root2, Bpk2, 25);
  pack_b_kernel<<<(64 * 64 + 255) / 256, blk, 0, stream>>>(m1w, m1w, m1pk, 0);
  cvt_x_kernel<<<(N * 64 + 255) / 256, blk, 0, stream>>>(x, Xbf, N * 64);

  // ----- layer 1 (K=3, K2=9): fused zbuild+GEMM, bf16 out -----
  spline_layer_kernel<3, 9, 1><<<nbF, blk, 0, stream>>>(
      cT3, offs, prow, deg, Xbf, Bpk1, b1, h1bf, N);

  // ----- layer 2 (K=5, K2=25): fused zbuild+GEMM, bf16 out -----
  spline_layer_kernel<5, 25, 1><<<nbF, blk, 0, stream>>>(
      cT5, offs, prow, deg, h1bf, Bpk2, b2, h2bf, N);

  // ----- fused MLP head -----
  head_kernel<<<nbH, blk, 0, stream>>>(h2bf, m1pk, m1b, m2w, m2b, out, N);
}

// Round 18
// 408.103 us; speedup vs baseline: 1.5406x; 1.5406x over previous
//
#include <hip/hip_runtime.h>
#include <hip/hip_bf16.h>

typedef __attribute__((ext_vector_type(8))) short short8;
typedef __attribute__((ext_vector_type(4))) float floatx4;
typedef __attribute__((ext_vector_type(16))) float floatx16;

__device__ __forceinline__ unsigned short f2bf(float x) {
  __hip_bfloat16 h = __float2bfloat16(x);
  return __builtin_bit_cast(unsigned short, h);
}
__device__ __forceinline__ float bf2f(unsigned short u) {
  return __builtin_bit_cast(float, (unsigned int)u << 16);
}

// ---------------------------------------------------------------------
// X (fp32) -> bf16 copy
// ---------------------------------------------------------------------
__global__ __launch_bounds__(256) void cvt_x_kernel(
    const float* __restrict__ X, unsigned short* __restrict__ Xbf, int n) {
  int i = blockIdx.x * 256 + threadIdx.x;
  if (i < n) Xbf[i] = f2bf(X[i]);
}

// ---------------------------------------------------------------------
// Pack extended weights [W | root] into MFMA B-fragment order.
// K2=0 packs just a 64x64 matrix from `root`.
// ---------------------------------------------------------------------
__global__ __launch_bounds__(256) void pack_b_kernel(
    const float* __restrict__ W, const float* __restrict__ root,
    unsigned short* __restrict__ Bpk, int K2) {
  int R = (K2 + 1) * 64;
  int total = 64 * R;
  int i = blockIdx.x * 256 + threadIdx.x;
  if (i >= total) return;
  int j = i & 7;
  int lane = (i >> 3) & 63;
  int rest = i >> 9;            // kc*4 + wv
  int wv = rest & 3, kc = rest >> 2;
  int o = wv * 16 + (lane & 15);
  int r = kc * 32 + ((lane >> 4) & 3) * 8 + j;
  int k = r >> 6, d = r & 63;
  float v = (k < K2) ? W[(k << 12) + (d << 6) + o] : root[(d << 6) + o];
  Bpk[i] = f2bf(v);
}

// ---------------------------------------------------------------------
// CSR build (padded to 16-edge chunks per node)
// ---------------------------------------------------------------------
__global__ __launch_bounds__(256) void zero_int_kernel(int* __restrict__ p, int n) {
  int i = blockIdx.x * 256 + threadIdx.x;
  if (i < n) p[i] = 0;
}

__global__ __launch_bounds__(256) void hist_kernel(
    const int* __restrict__ dst, int* __restrict__ deg, int nE) {
  int e = blockIdx.x * 256 + threadIdx.x;
  if (e < nE) atomicAdd(&deg[dst[e]], 1);
}

__global__ __launch_bounds__(256) void blocksum_kernel(
    const int* __restrict__ deg, int* __restrict__ partial, int N) {
  __shared__ int s[256];
  int t = threadIdx.x, i = blockIdx.x * 256 + t;
  s[t] = (i < N) ? ((deg[i] + 15) & ~15) : 0;   // padded degree
  __syncthreads();
  for (int off = 128; off > 0; off >>= 1) {
    if (t < off) s[t] += s[t + off];
    __syncthreads();
  }
  if (t == 0) partial[blockIdx.x] = s[0];
}

__global__ __launch_bounds__(256) void scanpartials_kernel(
    int* __restrict__ partial, int nb) {
  __shared__ int s[256];
  int t = threadIdx.x;
  int v = (t < nb) ? partial[t] : 0;
  s[t] = v;
  __syncthreads();
  for (int off = 1; off < 256; off <<= 1) {
    int x = (t >= off) ? s[t - off] : 0;
    __syncthreads();
    s[t] += x;
    __syncthreads();
  }
  if (t < nb) partial[t] = s[t] - v;
}

__global__ __launch_bounds__(256) void blockscan_kernel(
    const int* __restrict__ deg, const int* __restrict__ partial,
    int* __restrict__ prow, int* __restrict__ cursor, int N) {
  __shared__ int s[256];
  int t = threadIdx.x, i = blockIdx.x * 256 + t;
  int v = (i < N) ? ((deg[i] + 15) & ~15) : 0;
  s[t] = v;
  __syncthreads();
  for (int off = 1; off < 256; off <<= 1) {
    int x = (t >= off) ? s[t - off] : 0;
    __syncthreads();
    s[t] += x;
    __syncthreads();
  }
  if (i < N) {
    int excl = s[t] - v + partial[blockIdx.x];
    prow[i] = excl;
    cursor[i] = excl;
    if (i == N - 1) prow[N] = excl + v;
  }
}

// ---------------------------------------------------------------------
// Scatter: per edge write offs + raw attr (12B scattered — cheap).
// ---------------------------------------------------------------------
__global__ __launch_bounds__(256) void scatter_rec_kernel(
    const int* __restrict__ dst, const int* __restrict__ src,
    const float* __restrict__ attr, int* __restrict__ cursor,
    int* __restrict__ offs, float2* __restrict__ attr2, int nE) {
  int e = blockIdx.x * 256 + threadIdx.x;
  if (e >= nE) return;
  int pos = atomicAdd(&cursor[dst[e]], 1);
  offs[pos] = src[e] * 64;
  attr2[pos] = *(const float2*)&attr[2 * e];
}

// Mark padding slots with sentinel attr (coeff 0; off 0 safe).
__global__ __launch_bounds__(256) void pad_mark_kernel(
    const int* __restrict__ deg, const int* __restrict__ prow,
    int* __restrict__ offs, float2* __restrict__ attr2, int N) {
  int i = blockIdx.x * 256 + threadIdx.x;
  int node = i >> 4, s = i & 15;
  if (node >= N) return;
  int d = deg[node];
  int pd = (d + 15) & ~15;
  if (d + s >= pd) return;
  int pos = prow[node] + d + s;
  offs[pos] = 0;
  attr2[pos] = make_float2(-1.f, -1.f);
}

// ---------------------------------------------------------------------
// Coalesced coefficient build: thread = (chunk, col); col<32 -> cT5,
// col in [32,48) -> cT3. Each thread reads the chunk's 16 attr2 entries
// (L1-shared across the chunk's 48 threads), computes 16 coeffs, writes
// one contiguous 32B run. Values bit-identical to on-the-fly compute.
// ---------------------------------------------------------------------
__global__ __launch_bounds__(256) void coeff_build_kernel(
    const float2* __restrict__ attr2, const int* __restrict__ prow,
    unsigned short* __restrict__ cT3, unsigned short* __restrict__ cT5,
    int N) {
  int i = blockIdx.x * 256 + threadIdx.x;
  int chunk = i / 48, col = i - chunk * 48;
  int PE = prow[N];                  // multiple of 16
  if (chunk * 16 >= PE) return;

  unsigned short c[16];
  if (col < 32) {
    int mi0 = (col < 25) ? (col % 5) : -3;
    int mi1 = (col < 25) ? (col / 5) : -3;
#pragma unroll
    for (int kp = 0; kp < 16; ++kp) {
      float2 a = attr2[(size_t)chunk * 16 + kp];
      float coeff = 0.f;
      if (a.x >= 0.f) {
        float u = a.x * 4.f, v = a.y * 4.f;
        int l0 = min((int)u, 3), l1 = min((int)v, 3);
        float f0 = u - (float)l0, f1 = v - (float)l1;
        float su = (mi0 == l0) ? (1.f - f0) : ((mi0 == l0 + 1) ? f0 : 0.f);
        float sv = (mi1 == l1) ? (1.f - f1) : ((mi1 == l1 + 1) ? f1 : 0.f);
        coeff = su * sv;
      }
      c[kp] = f2bf(coeff);
    }
    unsigned short* dst = &cT5[(size_t)chunk * 512 + col * 16];
    *(floatx4*)dst = *(floatx4*)&c[0];
    *(floatx4*)(dst + 8) = *(floatx4*)&c[8];
  } else {
    int cc = col - 32;
    int mi0 = (cc < 9) ? (cc % 3) : -3;
    int mi1 = (cc < 9) ? (cc / 3) : -3;
#pragma unroll
    for (int kp = 0; kp < 16; ++kp) {
      float2 a = attr2[(size_t)chunk * 16 + kp];
      float coeff = 0.f;
      if (a.x >= 0.f) {
        float u = a.x * 2.f, v = a.y * 2.f;
        int l0 = min((int)u, 1), l1 = min((int)v, 1);
        float f0 = u - (float)l0, f1 = v - (float)l1;
        float su = (mi0 == l0) ? (1.f - f0) : ((mi0 == l0 + 1) ? f0 : 0.f);
        float sv = (mi1 == l1) ? (1.f - f1) : ((mi1 == l1 + 1) ? f1 : 0.f);
        coeff = su * sv;
      }
      c[kp] = f2bf(coeff);
    }
    unsigned short* dst = &cT3[(size_t)chunk * 256 + cc * 16];
    *(floatx4*)dst = *(floatx4*)&c[0];
    *(floatx4*)(dst + 8) = *(floatx4*)&c[8];
  }
}

// ---------------------------------------------------------------------
// FUSED spline layer: block = 4 waves = 16 dst nodes (4 nodes/wave).
// Phase 1: per 16-edge chunk, A-fragment is ONE coalesced 16B/lane load
//   from the precomputed cT stream, offs are 8 broadcast loads, then 16
//   bf16 row-gathers -> 2 MFMAs.
// Phase 2: out[16x64] = ELU([Az | X] @ Bpk + b); root row read from input.
// ---------------------------------------------------------------------
template <int K, int K2, int OUTBF>
__global__ __launch_bounds__(256) void spline_layer_kernel(
    const unsigned short* __restrict__ cT, const int* __restrict__ offs,
    const int* __restrict__ prow, const int* __restrict__ deg,
    const unsigned short* __restrict__ Xbf, const unsigned short* __restrict__ Bpk,
    const float* __restrict__ bias, void* __restrict__ outv, int N) {
  constexpr int RZ = K2 * 64;          // bucket columns: 576 / 1600
  constexpr int AS = RZ + 8;           // LDS row stride (shorts)
  constexpr int NKZ = RZ / 32;         // 18 / 50
  constexpr int NKC = (K2 + 1) * 2;    // 20 / 52
  constexpr int CSTRIDE = (K == 3) ? 256 : 512;
  __shared__ unsigned short As[16 * AS];
  const int t = threadIdx.x, w = t >> 6, lane = t & 63;
  const int nodeBase = blockIdx.x * 16;

  const int col = lane & 31, half = lane >> 5;

  // ---------- phase 1: zbuild 4 nodes per wave into LDS ----------
  for (int g = 0; g < 4; ++g) {
    const int row = w * 4 + g;
    const int node = nodeBase + row;
    if (node < N) {
      floatx16 d0, d1;
#pragma unroll
      for (int i = 0; i < 16; ++i) { d0[i] = 0.f; d1[i] = 0.f; }

      const int beg = prow[node], endp = prow[node + 1];
      for (int c0 = beg; c0 < endp; c0 += 16) {
        const int chunk = c0 >> 4;
        short8 A;
        if (K == 3) {
          short8 tmp = *(const short8*)&cT[(size_t)chunk * CSTRIDE +
                                           (col & 15) * 16 + half * 8];
          short8 zero = {0, 0, 0, 0, 0, 0, 0, 0};
          A = (col < 16) ? tmp : zero;
        } else {
          A = *(const short8*)&cT[(size_t)chunk * CSTRIDE + col * 16 + half * 8];
        }
        int offj[8];
#pragma unroll
        for (int j = 0; j < 8; ++j) offj[j] = offs[c0 + half * 8 + j];
        short8 Blo, Bhi;
#pragma unroll
        for (int j = 0; j < 8; ++j) {
          Blo[j] = (short)Xbf[offj[j] + col];
          Bhi[j] = (short)Xbf[offj[j] + 32 + col];
        }
        d0 = __builtin_amdgcn_mfma_f32_32x32x16_bf16(A, Blo, d0, 0, 0, 0);
        d1 = __builtin_amdgcn_mfma_f32_32x32x16_bf16(A, Bhi, d1, 0, 0, 0);
      }

      const float inv = 1.f / (float)max(deg[node], 1);
#pragma unroll
      for (int reg = 0; reg < 16; ++reg) {
        int r = (reg & 3) + 8 * (reg >> 2) + 4 * half;
        if (r < K2) {
          As[row * AS + r * 64 + col] = f2bf(d0[reg] * inv);
          As[row * AS + r * 64 + 32 + col] = f2bf(d1[reg] * inv);
        }
      }
    } else {
      for (int i = lane; i < RZ; i += 64) As[row * AS + i] = 0;
    }
  }
  __syncthreads();

  // ---------- phase 2: 16 x R x 64 GEMM + bias + ELU ----------
  const int mrow = lane & 15, q = lane >> 4;
  const int anode = min(nodeBase + mrow, N - 1);  // root row (clamped; garbage
                                                  // only hits discarded rows)
  floatx4 acc = {0.f, 0.f, 0.f, 0.f};
#pragma unroll
  for (int kc = 0; kc < NKC; ++kc) {
    short8 a;
    if (kc < NKZ)
      a = *(const short8*)&As[mrow * AS + kc * 32 + q * 8];
    else
      a = *(const short8*)&Xbf[(size_t)anode * 64 + (kc - NKZ) * 32 + q * 8];
    short8 b = *(const short8*)&Bpk[(((size_t)kc * 4 + w) * 64 + lane) * 8];
    acc = __builtin_amdgcn_mfma_f32_16x16x32_bf16(a, b, acc, 0, 0, 0);
  }

  const int o = w * 16 + mrow;
  const float bv = bias[o];
#pragma unroll
  for (int reg = 0; reg < 4; ++reg) {
    int node = nodeBase + q * 4 + reg;
    if (node < N) {
      float v = acc[reg] + bv;
      v = v > 0.f ? v : (expf(v) - 1.f);
      if (OUTBF)
        ((unsigned short*)outv)[(size_t)node * 64 + o] = f2bf(v);
      else
        ((float*)outv)[(size_t)node * 64 + o] = v;
    }
  }
}

// ---------------------------------------------------------------------
// FUSED MLP head: out = relu( relu(h2 @ m1w + m1b) @ m2w + m2b )
// ---------------------------------------------------------------------
__global__ __launch_bounds__(256) void head_kernel(
    const unsigned short* __restrict__ h2bf, const unsigned short* __restrict__ m1pk,
    const float* __restrict__ m1b, const float* __restrict__ m2w,
    const float* __restrict__ m2b, float* __restrict__ out, int N) {
  __shared__ unsigned short Hs[64 * 72];
  __shared__ unsigned short Ts[64 * 72];
  __shared__ float W2s[512];
  const int t = threadIdx.x, w = t >> 6, lane = t & 63;
  const int n0 = blockIdx.x * 64;

  for (int i = t; i < 512; i += 256) {
    int row = i >> 3, cg = i & 7;
    int n = n0 + row;
    floatx4 val = {0.f, 0.f, 0.f, 0.f};
    if (n < N) val = *(const floatx4*)&h2bf[(size_t)n * 64 + cg * 8];
    *(floatx4*)&Hs[row * 72 + cg * 8] = val;
  }
  for (int i = t; i < 512; i += 256) W2s[i] = m2w[i];
  __syncthreads();

  const int mrow = lane & 15, q = lane >> 4;
  const int o = w * 16 + mrow;
  const float bv = m1b[o];
#pragma unroll
  for (int rg = 0; rg < 4; ++rg) {
    floatx4 acc = {0.f, 0.f, 0.f, 0.f};
#pragma unroll
    for (int kc = 0; kc < 2; ++kc) {
      short8 a = *(const short8*)&Hs[(rg * 16 + mrow) * 72 + kc * 32 + q * 8];
      short8 b = *(const short8*)&m1pk[(((size_t)kc * 4 + w) * 64 + lane) * 8];
      acc = __builtin_amdgcn_mfma_f32_16x16x32_bf16(a, b, acc, 0, 0, 0);
    }
#pragma unroll
    for (int reg = 0; reg < 4; ++reg) {
      int row = rg * 16 + q * 4 + reg;
      float v = acc[reg] + bv;
      Ts[row * 72 + o] = f2bf(v > 0.f ? v : 0.f);
    }
  }
  __syncthreads();

  for (int i = t; i < 512; i += 256) {
    int nl = i >> 3, c = i & 7;
    int n = n0 + nl;
    if (n >= N) continue;
    float s = m2b[c];
    for (int d = 0; d < 64; ++d) s += bf2f(Ts[nl * 72 + d]) * W2s[d * 8 + c];
    out[(size_t)n * 8 + c] = s > 0.f ? s : 0.f;
  }
}

// ---------------------------------------------------------------------
extern "C" void kernel_launch(void* const* d_in, const int* in_sizes, int n_in,
                              void* d_out, int out_size, void* d_ws, size_t ws_size,
                              hipStream_t stream) {
  const float* x     = (const float*)d_in[0];
  const int*   ei    = (const int*)d_in[1];
  const float* attr  = (const float*)d_in[2];
  const float* W1    = (const float*)d_in[3];
  const float* root1 = (const float*)d_in[4];
  const float* b1    = (const float*)d_in[5];
  const float* W2    = (const float*)d_in[6];
  const float* root2 = (const float*)d_in[7];
  const float* b2    = (const float*)d_in[8];
  const float* m1w   = (const float*)d_in[9];
  const float* m1b   = (const float*)d_in[10];
  const float* m2w   = (const float*)d_in[11];
  const float* m2b   = (const float*)d_in[12];

  const int N  = in_sizes[0] / 64;
  const int nE = in_sizes[1] / 2;
  const int* src  = ei;
  const int* dstv = ei + nE;
  float* out = (float*)d_out;

  // workspace layout
  const size_t maxPE = (size_t)nE + 16 * (size_t)N;   // padded-edge bound
  const size_t maxChunks = maxPE / 16;
  int* deg     = (int*)d_ws;
  int* prow    = deg + N;                 // N+1
  int* cursor  = prow + (N + 1);
  int* partial = cursor + N;              // 256
  char* pbase = (char*)(partial + 256);
  pbase = (char*)(((uintptr_t)pbase + 15) & ~(uintptr_t)15);
  int* offs = (int*)pbase;                                // maxPE
  float2* attr2 = (float2*)(offs + maxPE);                // maxPE * 8B
  unsigned short* cT3 = (unsigned short*)(attr2 + maxPE); // maxChunks*256
  unsigned short* cT5 = cT3 + maxChunks * 256;            // maxChunks*512
  unsigned short* Xbf  = cT5 + maxChunks * 512;           // N*64
  unsigned short* h1bf = Xbf + (size_t)N * 64;            // N*64
  unsigned short* h2bf = h1bf + (size_t)N * 64;           // N*64
  unsigned short* Bpk1 = h2bf + (size_t)N * 64;           // 64*640
  unsigned short* Bpk2 = Bpk1 + 64 * 640;                 // 64*1664
  unsigned short* m1pk = Bpk2 + 64 * 1664;                // 64*64

  dim3 blk(256);
  int nbN  = (N + 255) / 256;
  int nbE  = (nE + 255) / 256;
  int nbP  = (N * 16 + 255) / 256;
  int nbC  = (int)((maxChunks * 48 + 255) / 256);
  int nbF  = (N + 15) / 16;
  int nbH  = (N + 63) / 64;

  // ----- CSR build (padded; graph identical both layers) -----
  zero_int_kernel<<<nbN, blk, 0, stream>>>(deg, N);
  hist_kernel<<<nbE, blk, 0, stream>>>(dstv, deg, nE);
  blocksum_kernel<<<nbN, blk, 0, stream>>>(deg, partial, N);
  scanpartials_kernel<<<1, blk, 0, stream>>>(partial, nbN);
  blockscan_kernel<<<nbN, blk, 0, stream>>>(deg, partial, prow, cursor, N);
  scatter_rec_kernel<<<nbE, blk, 0, stream>>>(dstv, src, attr, cursor,
                                              offs, attr2, nE);
  pad_mark_kernel<<<nbP, blk, 0, stream>>>(deg, prow, offs, attr2, N);
  coeff_build_kernel<<<nbC, blk, 0, stream>>>(attr2, prow, cT3, cT5, N);

  // ----- weight / input prep -----
  pack_b_kernel<<<(64 * 640 + 255) / 256, blk, 0, stream>>>(W1, root1, Bpk1, 9);
  pack_b_kernel<<<(64 * 1664 + 255) / 256, blk, 0, stream>>>(W2, root2, Bpk2, 25);
  pack_b_kernel<<<(64 * 64 + 255) / 256, blk, 0, stream>>>(m1w, m1w, m1pk, 0);
  cvt_x_kernel<<<(N * 64 + 255) / 256, blk, 0, stream>>>(x, Xbf, N * 64);

  // ----- layer 1 (K=3, K2=9): fused zbuild+GEMM, bf16 out -----
  spline_layer_kernel<3, 9, 1><<<nbF, blk, 0, stream>>>(
      cT3, offs, prow, deg, Xbf, Bpk1, b1, h1bf, N);

  // ----- layer 2 (K=5, K2=25): fused zbuild+GEMM, bf16 out -----
  spline_layer_kernel<5, 25, 1><<<nbF, blk, 0, stream>>>(
      cT5, offs, prow, deg, h1bf, Bpk2, b2, h2bf, N);

  // ----- fused MLP head -----
  head_kernel<<<nbH, blk, 0, stream>>>(h2bf, m1pk, m1b, m2w, m2b, out, N);
}

// Round 19
// 359.624 us; speedup vs baseline: 1.7482x; 1.1348x over previous
//
#include <hip/hip_runtime.h>
#include <hip/hip_bf16.h>

typedef __attribute__((ext_vector_type(8))) short short8;
typedef __attribute__((ext_vector_type(4))) float floatx4;
typedef __attribute__((ext_vector_type(16))) float floatx16;

__device__ __forceinline__ unsigned short f2bf(float x) {
  __hip_bfloat16 h = __float2bfloat16(x);
  return __builtin_bit_cast(unsigned short, h);
}
__device__ __forceinline__ float bf2f(unsigned short u) {
  return __builtin_bit_cast(float, (unsigned int)u << 16);
}

// ---------------------------------------------------------------------
// X (fp32) -> bf16 copy
// ---------------------------------------------------------------------
__global__ __launch_bounds__(256) void cvt_x_kernel(
    const float* __restrict__ X, unsigned short* __restrict__ Xbf, int n) {
  int i = blockIdx.x * 256 + threadIdx.x;
  if (i < n) Xbf[i] = f2bf(X[i]);
}

// ---------------------------------------------------------------------
// Pack extended weights [W | root] into MFMA B-fragment order.
// K2=0 packs just a 64x64 matrix from `root`.
// ---------------------------------------------------------------------
__global__ __launch_bounds__(256) void pack_b_kernel(
    const float* __restrict__ W, const float* __restrict__ root,
    unsigned short* __restrict__ Bpk, int K2) {
  int R = (K2 + 1) * 64;
  int total = 64 * R;
  int i = blockIdx.x * 256 + threadIdx.x;
  if (i >= total) return;
  int j = i & 7;
  int lane = (i >> 3) & 63;
  int rest = i >> 9;            // kc*4 + wv
  int wv = rest & 3, kc = rest >> 2;
  int o = wv * 16 + (lane & 15);
  int r = kc * 32 + ((lane >> 4) & 3) * 8 + j;
  int k = r >> 6, d = r & 63;
  float v = (k < K2) ? W[(k << 12) + (d << 6) + o] : root[(d << 6) + o];
  Bpk[i] = f2bf(v);
}

// ---------------------------------------------------------------------
// CSR build (padded to 16-edge chunks per node)
// ---------------------------------------------------------------------
__global__ __launch_bounds__(256) void zero_int_kernel(int* __restrict__ p, int n) {
  int i = blockIdx.x * 256 + threadIdx.x;
  if (i < n) p[i] = 0;
}

__global__ __launch_bounds__(256) void hist_kernel(
    const int* __restrict__ dst, int* __restrict__ deg, int nE) {
  int e = blockIdx.x * 256 + threadIdx.x;
  if (e < nE) atomicAdd(&deg[dst[e]], 1);
}

__global__ __launch_bounds__(256) void blocksum_kernel(
    const int* __restrict__ deg, int* __restrict__ partial, int N) {
  __shared__ int s[256];
  int t = threadIdx.x, i = blockIdx.x * 256 + t;
  s[t] = (i < N) ? ((deg[i] + 15) & ~15) : 0;   // padded degree
  __syncthreads();
  for (int off = 128; off > 0; off >>= 1) {
    if (t < off) s[t] += s[t + off];
    __syncthreads();
  }
  if (t == 0) partial[blockIdx.x] = s[0];
}

__global__ __launch_bounds__(256) void scanpartials_kernel(
    int* __restrict__ partial, int nb) {
  __shared__ int s[256];
  int t = threadIdx.x;
  int v = (t < nb) ? partial[t] : 0;
  s[t] = v;
  __syncthreads();
  for (int off = 1; off < 256; off <<= 1) {
    int x = (t >= off) ? s[t - off] : 0;
    __syncthreads();
    s[t] += x;
    __syncthreads();
  }
  if (t < nb) partial[t] = s[t] - v;
}

__global__ __launch_bounds__(256) void blockscan_kernel(
    const int* __restrict__ deg, const int* __restrict__ partial,
    int* __restrict__ prow, int* __restrict__ cursor, int N) {
  __shared__ int s[256];
  int t = threadIdx.x, i = blockIdx.x * 256 + t;
  int v = (i < N) ? ((deg[i] + 15) & ~15) : 0;
  s[t] = v;
  __syncthreads();
  for (int off = 1; off < 256; off <<= 1) {
    int x = (t >= off) ? s[t - off] : 0;
    __syncthreads();
    s[t] += x;
    __syncthreads();
  }
  if (i < N) {
    int excl = s[t] - v + partial[blockIdx.x];
    prow[i] = excl;
    cursor[i] = excl;
    if (i == N - 1) prow[N] = excl + v;
  }
}

// ---------------------------------------------------------------------
// Scatter: per edge write offs + raw attr (12B scattered — cheap).
// ---------------------------------------------------------------------
__global__ __launch_bounds__(256) void scatter_rec_kernel(
    const int* __restrict__ dst, const int* __restrict__ src,
    const float* __restrict__ attr, int* __restrict__ cursor,
    int* __restrict__ offs, float2* __restrict__ attr2, int nE) {
  int e = blockIdx.x * 256 + threadIdx.x;
  if (e >= nE) return;
  int pos = atomicAdd(&cursor[dst[e]], 1);
  offs[pos] = src[e] * 64;
  attr2[pos] = *(const float2*)&attr[2 * e];
}

// Mark padding slots with sentinel attr (coeff 0; off 0 safe).
__global__ __launch_bounds__(256) void pad_mark_kernel(
    const int* __restrict__ deg, const int* __restrict__ prow,
    int* __restrict__ offs, float2* __restrict__ attr2, int N) {
  int i = blockIdx.x * 256 + threadIdx.x;
  int node = i >> 4, s = i & 15;
  if (node >= N) return;
  int d = deg[node];
  int pd = (d + 15) & ~15;
  if (d + s >= pd) return;
  int pos = prow[node] + d + s;
  offs[pos] = 0;
  attr2[pos] = make_float2(-1.f, -1.f);
}

// ---------------------------------------------------------------------
// Sparse coefficient build: block = 16 chunks x 16 edge-slots.
// Zeroed LDS tile = default (pad) coefficient; each thread computes its
// edge's FOUR nonzero products per K (bit-identical fp32 math + f2bf)
// and scatter-writes 8 bf16 into race-free LDS slots; block then flushes
// the tile with fully-coalesced float4 stores. ~20x less VALU than the
// per-(chunk,col) dense build (R18: 83us @ 76% VALUBusy).
// ---------------------------------------------------------------------
__global__ __launch_bounds__(256) void coeff_build_kernel(
    const float2* __restrict__ attr2, const int* __restrict__ prow,
    unsigned short* __restrict__ cT3, unsigned short* __restrict__ cT5,
    int N) {
  __shared__ unsigned short t5[16 * 512];
  __shared__ unsigned short t3[16 * 256];
  const int t = threadIdx.x;
  const int PE = prow[N];

  // zero tiles (24 KB): 6144 ints / 256 threads = 24 each
  for (int i = t; i < 4096; i += 256) ((int*)t5)[i] = 0;
  for (int i = t; i < 2048; i += 256) ((int*)t3)[i] = 0;
  __syncthreads();

  const int chunkL = t >> 4, kp = t & 15;
  const int pos = (blockIdx.x * 16 + chunkL) * 16 + kp;
  if (pos < PE) {
    float2 a = attr2[pos];
    if (a.x >= 0.f) {
      {  // K=5
        float u = a.x * 4.f, v = a.y * 4.f;
        int l0 = min((int)u, 3), l1 = min((int)v, 3);
        float f0 = u - (float)l0, f1 = v - (float)l1;
        float s0 = 1.f - f0, s1 = 1.f - f1;
        unsigned short* b = &t5[chunkL * 512 + kp];
        b[(l0 + l1 * 5) * 16]       = f2bf(s0 * s1);
        b[(l0 + 1 + l1 * 5) * 16]   = f2bf(f0 * s1);
        b[(l0 + (l1 + 1) * 5) * 16] = f2bf(s0 * f1);
        b[(l0 + 1 + (l1 + 1) * 5) * 16] = f2bf(f0 * f1);
      }
      {  // K=3
        float u = a.x * 2.f, v = a.y * 2.f;
        int l0 = min((int)u, 1), l1 = min((int)v, 1);
        float f0 = u - (float)l0, f1 = v - (float)l1;
        float s0 = 1.f - f0, s1 = 1.f - f1;
        unsigned short* b = &t3[chunkL * 256 + kp];
        b[(l0 + l1 * 3) * 16]       = f2bf(s0 * s1);
        b[(l0 + 1 + l1 * 3) * 16]   = f2bf(f0 * s1);
        b[(l0 + (l1 + 1) * 3) * 16] = f2bf(s0 * f1);
        b[(l0 + 1 + (l1 + 1) * 3) * 16] = f2bf(f0 * f1);
      }
    }
  }
  __syncthreads();

  // coalesced flush: tile layout matches global chunk-major layout
  {
    floatx4* dst = (floatx4*)&cT5[(size_t)blockIdx.x * 16 * 512];
    const floatx4* srcp = (const floatx4*)t5;
#pragma unroll
    for (int k = 0; k < 4; ++k) dst[t + k * 256] = srcp[t + k * 256];
  }
  {
    floatx4* dst = (floatx4*)&cT3[(size_t)blockIdx.x * 16 * 256];
    const floatx4* srcp = (const floatx4*)t3;
#pragma unroll
    for (int k = 0; k < 2; ++k) dst[t + k * 256] = srcp[t + k * 256];
  }
}

// ---------------------------------------------------------------------
// FUSED spline layer: block = 4 waves = 16 dst nodes (4 nodes/wave).
// Phase 1: per 16-edge chunk, A-fragment is ONE coalesced 16B/lane load
//   from the precomputed cT stream, offs are 8 broadcast loads, then 16
//   bf16 row-gathers -> 2 MFMAs.
// Phase 2: out[16x64] = ELU([Az | X] @ Bpk + b); root row read from input.
// ---------------------------------------------------------------------
template <int K, int K2, int OUTBF>
__global__ __launch_bounds__(256) void spline_layer_kernel(
    const unsigned short* __restrict__ cT, const int* __restrict__ offs,
    const int* __restrict__ prow, const int* __restrict__ deg,
    const unsigned short* __restrict__ Xbf, const unsigned short* __restrict__ Bpk,
    const float* __restrict__ bias, void* __restrict__ outv, int N) {
  constexpr int RZ = K2 * 64;          // bucket columns: 576 / 1600
  constexpr int AS = RZ + 8;           // LDS row stride (shorts)
  constexpr int NKZ = RZ / 32;         // 18 / 50
  constexpr int NKC = (K2 + 1) * 2;    // 20 / 52
  constexpr int CSTRIDE = (K == 3) ? 256 : 512;
  __shared__ unsigned short As[16 * AS];
  const int t = threadIdx.x, w = t >> 6, lane = t & 63;
  const int nodeBase = blockIdx.x * 16;

  const int col = lane & 31, half = lane >> 5;

  // ---------- phase 1: zbuild 4 nodes per wave into LDS ----------
  for (int g = 0; g < 4; ++g) {
    const int row = w * 4 + g;
    const int node = nodeBase + row;
    if (node < N) {
      floatx16 d0, d1;
#pragma unroll
      for (int i = 0; i < 16; ++i) { d0[i] = 0.f; d1[i] = 0.f; }

      const int beg = prow[node], endp = prow[node + 1];
      for (int c0 = beg; c0 < endp; c0 += 16) {
        const int chunk = c0 >> 4;
        short8 A;
        if (K == 3) {
          short8 tmp = *(const short8*)&cT[(size_t)chunk * CSTRIDE +
                                           (col & 15) * 16 + half * 8];
          short8 zero = {0, 0, 0, 0, 0, 0, 0, 0};
          A = (col < 16) ? tmp : zero;
        } else {
          A = *(const short8*)&cT[(size_t)chunk * CSTRIDE + col * 16 + half * 8];
        }
        int offj[8];
#pragma unroll
        for (int j = 0; j < 8; ++j) offj[j] = offs[c0 + half * 8 + j];
        short8 Blo, Bhi;
#pragma unroll
        for (int j = 0; j < 8; ++j) {
          Blo[j] = (short)Xbf[offj[j] + col];
          Bhi[j] = (short)Xbf[offj[j] + 32 + col];
        }
        d0 = __builtin_amdgcn_mfma_f32_32x32x16_bf16(A, Blo, d0, 0, 0, 0);
        d1 = __builtin_amdgcn_mfma_f32_32x32x16_bf16(A, Bhi, d1, 0, 0, 0);
      }

      const float inv = 1.f / (float)max(deg[node], 1);
#pragma unroll
      for (int reg = 0; reg < 16; ++reg) {
        int r = (reg & 3) + 8 * (reg >> 2) + 4 * half;
        if (r < K2) {
          As[row * AS + r * 64 + col] = f2bf(d0[reg] * inv);
          As[row * AS + r * 64 + 32 + col] = f2bf(d1[reg] * inv);
        }
      }
    } else {
      for (int i = lane; i < RZ; i += 64) As[row * AS + i] = 0;
    }
  }
  __syncthreads();

  // ---------- phase 2: 16 x R x 64 GEMM + bias + ELU ----------
  const int mrow = lane & 15, q = lane >> 4;
  const int anode = min(nodeBase + mrow, N - 1);  // root row (clamped; garbage
                                                  // only hits discarded rows)
  floatx4 acc = {0.f, 0.f, 0.f, 0.f};
#pragma unroll
  for (int kc = 0; kc < NKC; ++kc) {
    short8 a;
    if (kc < NKZ)
      a = *(const short8*)&As[mrow * AS + kc * 32 + q * 8];
    else
      a = *(const short8*)&Xbf[(size_t)anode * 64 + (kc - NKZ) * 32 + q * 8];
    short8 b = *(const short8*)&Bpk[(((size_t)kc * 4 + w) * 64 + lane) * 8];
    acc = __builtin_amdgcn_mfma_f32_16x16x32_bf16(a, b, acc, 0, 0, 0);
  }

  const int o = w * 16 + mrow;
  const float bv = bias[o];
#pragma unroll
  for (int reg = 0; reg < 4; ++reg) {
    int node = nodeBase + q * 4 + reg;
    if (node < N) {
      float v = acc[reg] + bv;
      v = v > 0.f ? v : (expf(v) - 1.f);
      if (OUTBF)
        ((unsigned short*)outv)[(size_t)node * 64 + o] = f2bf(v);
      else
        ((float*)outv)[(size_t)node * 64 + o] = v;
    }
  }
}

// ---------------------------------------------------------------------
// FUSED MLP head: out = relu( relu(h2 @ m1w + m1b) @ m2w + m2b )
// ---------------------------------------------------------------------
__global__ __launch_bounds__(256) void head_kernel(
    const unsigned short* __restrict__ h2bf, const unsigned short* __restrict__ m1pk,
    const float* __restrict__ m1b, const float* __restrict__ m2w,
    const float* __restrict__ m2b, float* __restrict__ out, int N) {
  __shared__ unsigned short Hs[64 * 72];
  __shared__ unsigned short Ts[64 * 72];
  __shared__ float W2s[512];
  const int t = threadIdx.x, w = t >> 6, lane = t & 63;
  const int n0 = blockIdx.x * 64;

  for (int i = t; i < 512; i += 256) {
    int row = i >> 3, cg = i & 7;
    int n = n0 + row;
    floatx4 val = {0.f, 0.f, 0.f, 0.f};
    if (n < N) val = *(const floatx4*)&h2bf[(size_t)n * 64 + cg * 8];
    *(floatx4*)&Hs[row * 72 + cg * 8] = val;
  }
  for (int i = t; i < 512; i += 256) W2s[i] = m2w[i];
  __syncthreads();

  const int mrow = lane & 15, q = lane >> 4;
  const int o = w * 16 + mrow;
  const float bv = m1b[o];
#pragma unroll
  for (int rg = 0; rg < 4; ++rg) {
    floatx4 acc = {0.f, 0.f, 0.f, 0.f};
#pragma unroll
    for (int kc = 0; kc < 2; ++kc) {
      short8 a = *(const short8*)&Hs[(rg * 16 + mrow) * 72 + kc * 32 + q * 8];
      short8 b = *(const short8*)&m1pk[(((size_t)kc * 4 + w) * 64 + lane) * 8];
      acc = __builtin_amdgcn_mfma_f32_16x16x32_bf16(a, b, acc, 0, 0, 0);
    }
#pragma unroll
    for (int reg = 0; reg < 4; ++reg) {
      int row = rg * 16 + q * 4 + reg;
      float v = acc[reg] + bv;
      Ts[row * 72 + o] = f2bf(v > 0.f ? v : 0.f);
    }
  }
  __syncthreads();

  for (int i = t; i < 512; i += 256) {
    int nl = i >> 3, c = i & 7;
    int n = n0 + nl;
    if (n >= N) continue;
    float s = m2b[c];
    for (int d = 0; d < 64; ++d) s += bf2f(Ts[nl * 72 + d]) * W2s[d * 8 + c];
    out[(size_t)n * 8 + c] = s > 0.f ? s : 0.f;
  }
}

// ---------------------------------------------------------------------
extern "C" void kernel_launch(void* const* d_in, const int* in_sizes, int n_in,
                              void* d_out, int out_size, void* d_ws, size_t ws_size,
                              hipStream_t stream) {
  const float* x     = (const float*)d_in[0];
  const int*   ei    = (const int*)d_in[1];
  const float* attr  = (const float*)d_in[2];
  const float* W1    = (const float*)d_in[3];
  const float* root1 = (const float*)d_in[4];
  const float* b1    = (const float*)d_in[5];
  const float* W2    = (const float*)d_in[6];
  const float* root2 = (const float*)d_in[7];
  const float* b2    = (const float*)d_in[8];
  const float* m1w   = (const float*)d_in[9];
  const float* m1b   = (const float*)d_in[10];
  const float* m2w   = (const float*)d_in[11];
  const float* m2b   = (const float*)d_in[12];

  const int N  = in_sizes[0] / 64;
  const int nE = in_sizes[1] / 2;
  const int* src  = ei;
  const int* dstv = ei + nE;
  float* out = (float*)d_out;

  // workspace layout
  const size_t maxPE = (size_t)nE + 16 * (size_t)N;      // padded-edge bound
  const size_t maxChunks = (maxPE / 16 + 15) & ~(size_t)15;  // 16-aligned
  int* deg     = (int*)d_ws;
  int* prow    = deg + N;                 // N+1
  int* cursor  = prow + (N + 1);
  int* partial = cursor + N;              // 256
  char* pbase = (char*)(partial + 256);
  pbase = (char*)(((uintptr_t)pbase + 15) & ~(uintptr_t)15);
  int* offs = (int*)pbase;                                // maxPE
  float2* attr2 = (float2*)(offs + maxPE);                // maxPE * 8B
  unsigned short* cT3 = (unsigned short*)(attr2 + maxPE); // maxChunks*256
  unsigned short* cT5 = cT3 + maxChunks * 256;            // maxChunks*512
  unsigned short* Xbf  = cT5 + maxChunks * 512;           // N*64
  unsigned short* h1bf = Xbf + (size_t)N * 64;            // N*64
  unsigned short* h2bf = h1bf + (size_t)N * 64;           // N*64
  unsigned short* Bpk1 = h2bf + (size_t)N * 64;           // 64*640
  unsigned short* Bpk2 = Bpk1 + 64 * 640;                 // 64*1664
  unsigned short* m1pk = Bpk2 + 64 * 1664;                // 64*64

  dim3 blk(256);
  int nbN  = (N + 255) / 256;
  int nbE  = (nE + 255) / 256;
  int nbP  = (N * 16 + 255) / 256;
  int nbC  = (int)(maxChunks / 16);
  int nbF  = (N + 15) / 16;
  int nbH  = (N + 63) / 64;

  // ----- CSR build (padded; graph identical both layers) -----
  zero_int_kernel<<<nbN, blk, 0, stream>>>(deg, N);
  hist_kernel<<<nbE, blk, 0, stream>>>(dstv, deg, nE);
  blocksum_kernel<<<nbN, blk, 0, stream>>>(deg, partial, N);
  scanpartials_kernel<<<1, blk, 0, stream>>>(partial, nbN);
  blockscan_kernel<<<nbN, blk, 0, stream>>>(deg, partial, prow, cursor, N);
  scatter_rec_kernel<<<nbE, blk, 0, stream>>>(dstv, src, attr, cursor,
                                              offs, attr2, nE);
  pad_mark_kernel<<<nbP, blk, 0, stream>>>(deg, prow, offs, attr2, N);
  coeff_build_kernel<<<nbC, blk, 0, stream>>>(attr2, prow, cT3, cT5, N);

  // ----- weight / input prep -----
  pack_b_kernel<<<(64 * 640 + 255) / 256, blk, 0, stream>>>(W1, root1, Bpk1, 9);
  pack_b_kernel<<<(64 * 1664 + 255) / 256, blk, 0, stream>>>(W2, root2, Bpk2, 25);
  pack_b_kernel<<<(64 * 64 + 255) / 256, blk, 0, stream>>>(m1w, m1w, m1pk, 0);
  cvt_x_kernel<<<(N * 64 + 255) / 256, blk, 0, stream>>>(x, Xbf, N * 64);

  // ----- layer 1 (K=3, K2=9): fused zbuild+GEMM, bf16 out -----
  spline_layer_kernel<3, 9, 1><<<nbF, blk, 0, stream>>>(
      cT3, offs, prow, deg, Xbf, Bpk1, b1, h1bf, N);

  // ----- layer 2 (K=5, K2=25): fused zbuild+GEMM, bf16 out -----
  spline_layer_kernel<5, 25, 1><<<nbF, blk, 0, stream>>>(
      cT5, offs, prow, deg, h1bf, Bpk2, b2, h2bf, N);

  // ----- fused MLP head -----
  head_kernel<<<nbH, blk, 0, stream>>>(h2bf, m1pk, m1b, m2w, m2b, out, N);
}